// Round 5
// baseline (274.511 us; speedup 1.0000x reference)
//
#include <hip/hip_runtime.h>
#include <cstdint>
#include <cmath>

#define THREADS 256
#define LDP 6016         // padded leading dim for partials (multiple of 4)
#define MAXCHUNK 6       // covers N <= 6144 at 256 threads * float4
#define RGROUPS 8        // slab-groups in the reduce stage

// Slab column-sum: each block owns R contiguous ROWS of one matrix and streams
// them front-to-back (fully contiguous 24KB/row => DRAM row-buffer friendly).
// Thread t accumulates cols {c*1024 + 4t} for c in [0,6) in registers.
// P[z][slab][col] = sum_{r in slab} (W ? w[r] : 1) * A[r][col]
template <bool WEIGHTED>
__global__ void colsum_slab_kernel(const float* __restrict__ A0,
                                   const float* __restrict__ A1,
                                   const float* __restrict__ w0,
                                   const float* __restrict__ w1,
                                   float* __restrict__ P,
                                   int N, int nSlabs, int R) {
    const int z = blockIdx.y;
    const float* __restrict__ A = z ? A1 : A0;
    const float* __restrict__ w = z ? w1 : w0;
    float* Pm = P + (size_t)z * nSlabs * LDP;

    const int slab = blockIdx.x;
    int r0 = slab * R;
    int r1 = r0 + R;
    if (r1 > N) r1 = N;
    const int col0 = threadIdx.x * 4;

    float4 acc[MAXCHUNK];
#pragma unroll
    for (int c = 0; c < MAXCHUNK; ++c) acc[c] = float4{0.f, 0.f, 0.f, 0.f};

    const float* row = A + (size_t)r0 * N;
    for (int r = r0; r < r1; ++r, row += N) {
        float wr = WEIGHTED ? w[r] : 1.0f;
        float4 v[MAXCHUNK];
#pragma unroll
        for (int c = 0; c < MAXCHUNK; ++c) {
            int col = c * 1024 + col0;
            if (col < N) v[c] = *reinterpret_cast<const float4*>(row + col);
        }
#pragma unroll
        for (int c = 0; c < MAXCHUNK; ++c) {
            int col = c * 1024 + col0;
            if (col < N) {
                acc[c].x += wr * v[c].x;
                acc[c].y += wr * v[c].y;
                acc[c].z += wr * v[c].z;
                acc[c].w += wr * v[c].w;
            }
        }
    }
#pragma unroll
    for (int c = 0; c < MAXCHUNK; ++c) {
        int col = c * 1024 + col0;
        if (col < N)
            *reinterpret_cast<float4*>(&Pm[(size_t)slab * LDP + col]) = acc[c];
    }
}

// Reduce partials: out_z[col] += sum over a slab-group. grid (6, 2, RGROUPS).
// Only 6000*2*RGROUPS/4-ish atomics total; P is L2/L3-resident (just written).
__global__ void reduce_atomic_kernel(const float* __restrict__ P,
                                     float* __restrict__ out0,
                                     float* __restrict__ out1,
                                     int N, int nSlabs) {
    int col = blockIdx.x * (THREADS * 4) + threadIdx.x * 4;
    if (col >= N) return;
    int z = blockIdx.y;
    int chunk = (nSlabs + RGROUPS - 1) / RGROUPS;
    int i0 = blockIdx.z * chunk;
    int i1 = i0 + chunk;
    if (i1 > nSlabs) i1 = nSlabs;
    float* out = z ? out1 : out0;

    const float* p = P + (size_t)z * nSlabs * LDP + (size_t)i0 * LDP + col;
    float4 s0 = {0, 0, 0, 0}, s1 = {0, 0, 0, 0};
    int i = i0;
    for (; i + 2 <= i1; i += 2, p += 2 * LDP) {
        float4 a = *reinterpret_cast<const float4*>(p);
        float4 b = *reinterpret_cast<const float4*>(p + LDP);
        s0.x += a.x; s0.y += a.y; s0.z += a.z; s0.w += a.w;
        s1.x += b.x; s1.y += b.y; s1.z += b.z; s1.w += b.w;
    }
    if (i < i1) {
        float4 a = *reinterpret_cast<const float4*>(p);
        s0.x += a.x; s0.y += a.y; s0.z += a.z; s0.w += a.w;
    }
    atomicAdd(&out[col + 0], s0.x + s1.x);
    atomicAdd(&out[col + 1], s0.y + s1.y);
    atomicAdd(&out[col + 2], s0.z + s1.z);
    atomicAdd(&out[col + 3], s0.w + s1.w);
}

// Merged feature reductions for all 4 branches (contiguous grid-stride reads).
__global__ void feat_all_kernel(const float* __restrict__ emb1,
                                const float* __restrict__ emb2,
                                const float* __restrict__ eat1,
                                const float* __restrict__ eat2,
                                const float* __restrict__ c1,
                                const float* __restrict__ d1,
                                const float* __restrict__ c2,
                                const float* __restrict__ d2,
                                const float* __restrict__ ce1,
                                const float* __restrict__ ce2,
                                float* __restrict__ n1,
                                float* __restrict__ n2,
                                float* __restrict__ eg1,
                                float* __restrict__ eg2,
                                int Nn, int Ne) {
    int unit = blockIdx.y;
    const float *feat, *c, *d;
    float* out;
    int total, log2L;
    bool hasQ;
    if (unit == 0)      { feat = emb1; c = c1;  d = d1;      out = n1;  total = Nn * 32; log2L = 5; hasQ = true;  }
    else if (unit == 1) { feat = emb2; c = c2;  d = d2;      out = n2;  total = Nn * 32; log2L = 5; hasQ = true;  }
    else if (unit == 2) { feat = eat1; c = ce1; d = nullptr; out = eg1; total = Ne * 16; log2L = 4; hasQ = false; }
    else                { feat = eat2; c = ce2; d = nullptr; out = eg2; total = Ne * 16; log2L = 4; hasQ = false; }

    int stride = gridDim.x * blockDim.x;   // multiple of L
    int idx = blockIdx.x * blockDim.x + threadIdx.x;
    int L = 1 << log2L;
    int l = idx & (L - 1);
    float as = 0.f, ap = 0.f, aq = 0.f;
    for (int i = idx; i < total; i += stride) {
        float v = feat[i];
        int r = i >> log2L;
        as += v;
        ap += c[r] * v;
        if (hasQ) aq += d[r] * v;
    }
    atomicAdd(&out[l], as);
    atomicAdd(&out[L + l], ap);
    if (hasQ) atomicAdd(&out[2 * L + l], aq);
}

// scoring[b][k] = sum_{d,e} e1[d] * W[d,e,k] * e2[e]
__global__ void scoring_kernel(const float* __restrict__ Wn,
                               const float* __restrict__ We,
                               const float* __restrict__ n1,
                               const float* __restrict__ n2,
                               const float* __restrict__ eg1,
                               const float* __restrict__ eg2,
                               float* __restrict__ scoring) {
    int b = blockIdx.y;
    int chunk = blockIdx.x;
    const float *W, *e1, *e2;
    int total, log2D;
    if (b < 3) {
        W = Wn + (size_t)b * (64 * 64 * 16);
        e1 = n1 + (b == 2 ? 32 : 0);   // b0,b1: g_01 ; b2: g_12
        e2 = n2 + (b == 2 ? 32 : 0);
        total = 64 * 64 * 16;
        log2D = 6;
    } else {
        W = We;
        e1 = eg1;
        e2 = eg2;
        total = 32 * 32 * 16;
        log2D = 5;
    }
    int begin = chunk * 4096 + threadIdx.x;
    int end = (chunk + 1) * 4096;
    if (end > total) end = total;
    float acc = 0.f;
    for (int idx = begin; idx < end; idx += 256) {
        int de = idx >> 4;
        int e = de & ((1 << log2D) - 1);
        int dd = de >> log2D;
        acc += e1[dd] * e2[e] * W[idx];
    }
    __shared__ float red[256];
    red[threadIdx.x] = acc;
    __syncthreads();
    if (threadIdx.x < 16) {
        float s = 0.f;
        for (int t = threadIdx.x; t < 256; t += 16) s += red[t];
        atomicAdd(&scoring[b * 16 + threadIdx.x], s);
    }
}

// One block, 64 threads: block-term + relu -> MLPs -> sigmoid -> outputs.
__global__ void final_kernel(const float* __restrict__ scoring,
                             const float* __restrict__ n1,
                             const float* __restrict__ n2,
                             const float* __restrict__ eg1,
                             const float* __restrict__ eg2,
                             const float* __restrict__ Wbn,
                             const float* __restrict__ bn,
                             const float* __restrict__ Wbe,
                             const float* __restrict__ be,
                             const float* __restrict__ m1w,
                             const float* __restrict__ m1b,
                             const float* __restrict__ m2w,
                             const float* __restrict__ m2b,
                             const float* __restrict__ m3w,
                             const float* __restrict__ m3b,
                             const float* __restrict__ sw,
                             const float* __restrict__ sb,
                             const float* __restrict__ avg_v,
                             float* __restrict__ out) {
    __shared__ float sval[4][16];
    __shared__ float scores[4];
    int t = threadIdx.x;          // 64 threads
    int b = t >> 4, k = t & 15;

    float blk;
    if (b < 3) {
        const float* e1 = n1 + (b == 2 ? 32 : 0);
        const float* e2 = n2 + (b == 2 ? 32 : 0);
        const float* wb = Wbn + (size_t)b * (16 * 128) + k * 128;
        float s = 0.f;
        for (int j = 0; j < 64; ++j) s += wb[j] * e1[j];
        for (int j = 0; j < 64; ++j) s += wb[64 + j] * e2[j];
        blk = s + bn[b * 16 + k];
    } else {
        const float* wb = Wbe + k * 64;
        float s = 0.f;
        for (int j = 0; j < 32; ++j) s += wb[j] * eg1[j];
        for (int j = 0; j < 32; ++j) s += wb[32 + j] * eg2[j];
        blk = s + be[k];
    }
    float v = scoring[b * 16 + k] + blk;
    sval[b][k] = v > 0.f ? v : 0.f;
    __syncthreads();

    if (t < 4) {
        float h1[16], h2[8], h3[4];
        for (int o = 0; o < 16; ++o) {
            float a = m1b[t * 16 + o];
            for (int i = 0; i < 16; ++i) a += m1w[(t * 16 + o) * 16 + i] * sval[t][i];
            h1[o] = a > 0.f ? a : 0.f;
        }
        for (int o = 0; o < 8; ++o) {
            float a = m2b[t * 8 + o];
            for (int i = 0; i < 16; ++i) a += m2w[(t * 8 + o) * 16 + i] * h1[i];
            h2[o] = a > 0.f ? a : 0.f;
        }
        for (int o = 0; o < 4; ++o) {
            float a = m3b[t * 4 + o];
            for (int i = 0; i < 8; ++i) a += m3w[(t * 4 + o) * 8 + i] * h2[i];
            h3[o] = a > 0.f ? a : 0.f;
        }
        float z = sb[t];
        for (int i = 0; i < 4; ++i) z += sw[t * 4 + i] * h3[i];
        scores[t] = 1.0f / (1.0f + expf(-z));
    }
    __syncthreads();

    if (t == 0) {
        const int ord[4] = {0, 1, 3, 2};   // (nc, in, ec, ie)
        float av = avg_v[0];
        float acc = 0.f;
        for (int j = 0; j < 4; ++j) {
            float sc = scores[ord[j]];
            out[2 + j] = sc;
            acc += -logf(sc);
        }
        float ged = acc * av;
        out[1] = ged;
        out[0] = expf(-ged / av);
    }
}

extern "C" void kernel_launch(void* const* d_in, const int* in_sizes, int n_in,
                              void* d_out, int out_size, void* d_ws, size_t ws_size,
                              hipStream_t stream) {
    const float* emb1  = (const float*)d_in[0];
    const float* emb2  = (const float*)d_in[1];
    const float* adj1  = (const float*)d_in[2];
    const float* adj2  = (const float*)d_in[3];
    const float* eat1  = (const float*)d_in[4];
    const float* eat2  = (const float*)d_in[5];
    const float* eadj1 = (const float*)d_in[6];
    const float* eadj2 = (const float*)d_in[7];
    const float* avg_v = (const float*)d_in[8];
    const float* Wn    = (const float*)d_in[9];
    const float* Wbn   = (const float*)d_in[10];
    const float* bn    = (const float*)d_in[11];
    const float* We    = (const float*)d_in[12];
    const float* Wbe   = (const float*)d_in[13];
    const float* be    = (const float*)d_in[14];
    const float* m1w   = (const float*)d_in[15];
    const float* m1b   = (const float*)d_in[16];
    const float* m2w   = (const float*)d_in[17];
    const float* m2b   = (const float*)d_in[18];
    const float* m3w   = (const float*)d_in[19];
    const float* m3b   = (const float*)d_in[20];
    const float* sw    = (const float*)d_in[21];
    const float* sb    = (const float*)d_in[22];

    int Nn = in_sizes[0] / 32;   // 6000 nodes
    int Ne = in_sizes[4] / 16;   // 6000 edges
    int N = Nn;                  // == Ne here

    // Slab sizing: target R=12 (500 slabs), adapt to ws_size if needed.
    size_t availF = ws_size / 4;
    size_t reserveF = 8 * (size_t)N + 4096;          // small vectors + tail
    size_t perMat = (availF > reserveF) ? (availF - reserveF) / 2 : 0;
    int maxSlabs = (int)(perMat / LDP);
    int nSlabs = (N + 11) / 12;                      // 500
    if (nSlabs > maxSlabs) nSlabs = maxSlabs > 0 ? maxSlabs : 1;
    int R = (N + nSlabs - 1) / nSlabs;
    nSlabs = (N + R - 1) / R;

    float* ws  = (float*)d_ws;
    float* P   = ws;                       // [2][nSlabs][LDP] partials, reused per phase
    float* c1  = P + (size_t)2 * nSlabs * LDP;
    float* d1  = c1 + N;
    float* c2  = d1 + N;
    float* d2  = c2 + N;
    float* ce1 = d2 + N;
    float* ce2 = ce1 + N;
    float* n1  = ce2 + N;      // [s(32), p(32), q(32)]
    float* n2  = n1 + 96;
    float* eg1 = n2 + 96;      // [s(16), p(16)]
    float* eg2 = eg1 + 32;
    float* scoring = eg2 + 32; // [4][16]
    // zero all accumulated outputs: c1..d2,ce1,ce2 (6N) + n/eg/scoring (320)
    hipMemsetAsync(c1, 0, (6 * (size_t)N + 320) * sizeof(float), stream);

    dim3 blk(THREADS);
    dim3 gridS(nSlabs, 2);                               // slab passes
    dim3 gridR((N + THREADS * 4 - 1) / (THREADS * 4), 2, RGROUPS);

    // Phase 1: unweighted colsums of adj1+adj2
    colsum_slab_kernel<false><<<gridS, blk, 0, stream>>>(adj1, adj2, nullptr, nullptr, P, N, nSlabs, R);
    reduce_atomic_kernel<<<gridR, blk, 0, stream>>>(P, c1, c2, N, nSlabs);
    // Phase 2: weighted colsums (re-read adj1+adj2)
    colsum_slab_kernel<true ><<<gridS, blk, 0, stream>>>(adj1, adj2, c1, c2, P, N, nSlabs, R);
    reduce_atomic_kernel<<<gridR, blk, 0, stream>>>(P, d1, d2, N, nSlabs);
    // Phase 3: edge adjacency colsums
    colsum_slab_kernel<false><<<gridS, blk, 0, stream>>>(eadj1, eadj2, nullptr, nullptr, P, N, nSlabs, R);
    reduce_atomic_kernel<<<gridR, blk, 0, stream>>>(P, ce1, ce2, N, nSlabs);

    feat_all_kernel<<<dim3(16, 4), blk, 0, stream>>>(emb1, emb2, eat1, eat2,
                                                     c1, d1, c2, d2, ce1, ce2,
                                                     n1, n2, eg1, eg2, Nn, Ne);

    scoring_kernel<<<dim3(16, 4), blk, 0, stream>>>(Wn, We, n1, n2, eg1, eg2, scoring);

    final_kernel<<<1, 64, 0, stream>>>(scoring, n1, n2, eg1, eg2,
                                       Wbn, bn, Wbe, be,
                                       m1w, m1b, m2w, m2b, m3w, m3b, sw, sb,
                                       avg_v, (float*)d_out);
}

// Round 6
// 236.773 us; speedup vs baseline: 1.1594x; 1.1594x over previous
//
#include <hip/hip_runtime.h>
#include <cstdint>
#include <cmath>

#define THREADS 256
#define LDP 6016         // padded leading dim for partials (multiple of 4)
#define RGROUPS 8        // slab-groups in the reduce stage
#define SLAB_R 32        // rows per slab

// Column-sum tile kernel: grid (colChunks, nSlabs, 2 matrices).
// Each thread owns ONE float4 column group and walks SLAB_R rows, 8 rows
// per unrolled batch (8 independent named loads -> deep MLP), full occupancy.
// P[z][slab][col] = sum_{r in slab} (W ? w[r] : 1) * A[r][col]
template <bool WEIGHTED>
__global__ __launch_bounds__(THREADS, 8)
void colsum_tile_kernel(const float* __restrict__ A0,
                        const float* __restrict__ A1,
                        const float* __restrict__ w0,
                        const float* __restrict__ w1,
                        float* __restrict__ P,
                        int N, int nSlabs, int R) {
    const int z = blockIdx.z;
    const float* __restrict__ A = z ? A1 : A0;
    const float* __restrict__ wv = z ? w1 : w0;

    const int col = blockIdx.x * (THREADS * 4) + threadIdx.x * 4;
    if (col >= N) return;
    const int slab = blockIdx.y;
    int r0 = slab * R;
    int r1 = r0 + R;
    if (r1 > N) r1 = N;

    float ax = 0.f, ay = 0.f, az = 0.f, aw = 0.f;   // chain A
    float bx = 0.f, by = 0.f, bz = 0.f, bw = 0.f;   // chain B
    const float* p = A + (size_t)r0 * N + col;
    const size_t sN = (size_t)N;
    int r = r0;
    for (; r + 8 <= r1; r += 8, p += 8 * sN) {
        // 8 independent loads issued before any use
        float4 v0 = *reinterpret_cast<const float4*>(p + 0 * sN);
        float4 v1 = *reinterpret_cast<const float4*>(p + 1 * sN);
        float4 v2 = *reinterpret_cast<const float4*>(p + 2 * sN);
        float4 v3 = *reinterpret_cast<const float4*>(p + 3 * sN);
        float4 v4 = *reinterpret_cast<const float4*>(p + 4 * sN);
        float4 v5 = *reinterpret_cast<const float4*>(p + 5 * sN);
        float4 v6 = *reinterpret_cast<const float4*>(p + 6 * sN);
        float4 v7 = *reinterpret_cast<const float4*>(p + 7 * sN);
        float q0 = WEIGHTED ? wv[r + 0] : 1.f;
        float q1 = WEIGHTED ? wv[r + 1] : 1.f;
        float q2 = WEIGHTED ? wv[r + 2] : 1.f;
        float q3 = WEIGHTED ? wv[r + 3] : 1.f;
        float q4 = WEIGHTED ? wv[r + 4] : 1.f;
        float q5 = WEIGHTED ? wv[r + 5] : 1.f;
        float q6 = WEIGHTED ? wv[r + 6] : 1.f;
        float q7 = WEIGHTED ? wv[r + 7] : 1.f;
        ax += q0 * v0.x; ay += q0 * v0.y; az += q0 * v0.z; aw += q0 * v0.w;
        bx += q1 * v1.x; by += q1 * v1.y; bz += q1 * v1.z; bw += q1 * v1.w;
        ax += q2 * v2.x; ay += q2 * v2.y; az += q2 * v2.z; aw += q2 * v2.w;
        bx += q3 * v3.x; by += q3 * v3.y; bz += q3 * v3.z; bw += q3 * v3.w;
        ax += q4 * v4.x; ay += q4 * v4.y; az += q4 * v4.z; aw += q4 * v4.w;
        bx += q5 * v5.x; by += q5 * v5.y; bz += q5 * v5.z; bw += q5 * v5.w;
        ax += q6 * v6.x; ay += q6 * v6.y; az += q6 * v6.z; aw += q6 * v6.w;
        bx += q7 * v7.x; by += q7 * v7.y; bz += q7 * v7.z; bw += q7 * v7.w;
    }
    for (; r < r1; ++r, p += sN) {
        float4 v = *reinterpret_cast<const float4*>(p);
        float q = WEIGHTED ? wv[r] : 1.f;
        ax += q * v.x; ay += q * v.y; az += q * v.z; aw += q * v.w;
    }
    float4 o = {ax + bx, ay + by, az + bz, aw + bw};
    *reinterpret_cast<float4*>(&P[((size_t)z * nSlabs + slab) * LDP + col]) = o;
}

// Reduce partials: out_z[col] += sum over a slab-group. grid (colChunks, 2, RGROUPS).
__global__ void reduce_atomic_kernel(const float* __restrict__ P,
                                     float* __restrict__ out0,
                                     float* __restrict__ out1,
                                     int N, int nSlabs) {
    int col = blockIdx.x * (THREADS * 4) + threadIdx.x * 4;
    if (col >= N) return;
    int z = blockIdx.y;
    int chunk = (nSlabs + RGROUPS - 1) / RGROUPS;
    int i0 = blockIdx.z * chunk;
    int i1 = i0 + chunk;
    if (i1 > nSlabs) i1 = nSlabs;
    float* out = z ? out1 : out0;

    const float* p = P + ((size_t)z * nSlabs + i0) * LDP + col;
    float4 s0 = {0, 0, 0, 0}, s1 = {0, 0, 0, 0};
    int i = i0;
    for (; i + 2 <= i1; i += 2, p += 2 * LDP) {
        float4 a = *reinterpret_cast<const float4*>(p);
        float4 b = *reinterpret_cast<const float4*>(p + LDP);
        s0.x += a.x; s0.y += a.y; s0.z += a.z; s0.w += a.w;
        s1.x += b.x; s1.y += b.y; s1.z += b.z; s1.w += b.w;
    }
    if (i < i1) {
        float4 a = *reinterpret_cast<const float4*>(p);
        s0.x += a.x; s0.y += a.y; s0.z += a.z; s0.w += a.w;
    }
    atomicAdd(&out[col + 0], s0.x + s1.x);
    atomicAdd(&out[col + 1], s0.y + s1.y);
    atomicAdd(&out[col + 2], s0.z + s1.z);
    atomicAdd(&out[col + 3], s0.w + s1.w);
}

// Merged feature reductions for all 4 branches.
__global__ void feat_all_kernel(const float* __restrict__ emb1,
                                const float* __restrict__ emb2,
                                const float* __restrict__ eat1,
                                const float* __restrict__ eat2,
                                const float* __restrict__ c1,
                                const float* __restrict__ d1,
                                const float* __restrict__ c2,
                                const float* __restrict__ d2,
                                const float* __restrict__ ce1,
                                const float* __restrict__ ce2,
                                float* __restrict__ n1,
                                float* __restrict__ n2,
                                float* __restrict__ eg1,
                                float* __restrict__ eg2,
                                int Nn, int Ne) {
    int unit = blockIdx.y;
    const float *feat, *c, *d;
    float* out;
    int total, log2L;
    bool hasQ;
    if (unit == 0)      { feat = emb1; c = c1;  d = d1;      out = n1;  total = Nn * 32; log2L = 5; hasQ = true;  }
    else if (unit == 1) { feat = emb2; c = c2;  d = d2;      out = n2;  total = Nn * 32; log2L = 5; hasQ = true;  }
    else if (unit == 2) { feat = eat1; c = ce1; d = nullptr; out = eg1; total = Ne * 16; log2L = 4; hasQ = false; }
    else                { feat = eat2; c = ce2; d = nullptr; out = eg2; total = Ne * 16; log2L = 4; hasQ = false; }

    int stride = gridDim.x * blockDim.x;   // multiple of L
    int idx = blockIdx.x * blockDim.x + threadIdx.x;
    int L = 1 << log2L;
    int l = idx & (L - 1);
    float as = 0.f, ap = 0.f, aq = 0.f;
    for (int i = idx; i < total; i += stride) {
        float v = feat[i];
        int r = i >> log2L;
        as += v;
        ap += c[r] * v;
        if (hasQ) aq += d[r] * v;
    }
    atomicAdd(&out[l], as);
    atomicAdd(&out[L + l], ap);
    if (hasQ) atomicAdd(&out[2 * L + l], aq);
}

// scoring[b][k] = sum_{d,e} e1[d] * W[d,e,k] * e2[e]
__global__ void scoring_kernel(const float* __restrict__ Wn,
                               const float* __restrict__ We,
                               const float* __restrict__ n1,
                               const float* __restrict__ n2,
                               const float* __restrict__ eg1,
                               const float* __restrict__ eg2,
                               float* __restrict__ scoring) {
    int b = blockIdx.y;
    int chunk = blockIdx.x;
    const float *W, *e1, *e2;
    int total, log2D;
    if (b < 3) {
        W = Wn + (size_t)b * (64 * 64 * 16);
        e1 = n1 + (b == 2 ? 32 : 0);   // b0,b1: g_01 ; b2: g_12
        e2 = n2 + (b == 2 ? 32 : 0);
        total = 64 * 64 * 16;
        log2D = 6;
    } else {
        W = We;
        e1 = eg1;
        e2 = eg2;
        total = 32 * 32 * 16;
        log2D = 5;
    }
    int begin = chunk * 4096 + threadIdx.x;
    int end = (chunk + 1) * 4096;
    if (end > total) end = total;
    float acc = 0.f;
    for (int idx = begin; idx < end; idx += 256) {
        int de = idx >> 4;
        int e = de & ((1 << log2D) - 1);
        int dd = de >> log2D;
        acc += e1[dd] * e2[e] * W[idx];
    }
    __shared__ float red[256];
    red[threadIdx.x] = acc;
    __syncthreads();
    if (threadIdx.x < 16) {
        float s = 0.f;
        for (int t = threadIdx.x; t < 256; t += 16) s += red[t];
        atomicAdd(&scoring[b * 16 + threadIdx.x], s);
    }
}

// One block, 64 threads: block-term + relu -> MLPs -> sigmoid -> outputs.
__global__ void final_kernel(const float* __restrict__ scoring,
                             const float* __restrict__ n1,
                             const float* __restrict__ n2,
                             const float* __restrict__ eg1,
                             const float* __restrict__ eg2,
                             const float* __restrict__ Wbn,
                             const float* __restrict__ bn,
                             const float* __restrict__ Wbe,
                             const float* __restrict__ be,
                             const float* __restrict__ m1w,
                             const float* __restrict__ m1b,
                             const float* __restrict__ m2w,
                             const float* __restrict__ m2b,
                             const float* __restrict__ m3w,
                             const float* __restrict__ m3b,
                             const float* __restrict__ sw,
                             const float* __restrict__ sb,
                             const float* __restrict__ avg_v,
                             float* __restrict__ out) {
    __shared__ float sval[4][16];
    __shared__ float scores[4];
    int t = threadIdx.x;          // 64 threads
    int b = t >> 4, k = t & 15;

    float blk;
    if (b < 3) {
        const float* e1 = n1 + (b == 2 ? 32 : 0);
        const float* e2 = n2 + (b == 2 ? 32 : 0);
        const float* wb = Wbn + (size_t)b * (16 * 128) + k * 128;
        float s = 0.f;
        for (int j = 0; j < 64; ++j) s += wb[j] * e1[j];
        for (int j = 0; j < 64; ++j) s += wb[64 + j] * e2[j];
        blk = s + bn[b * 16 + k];
    } else {
        const float* wb = Wbe + k * 64;
        float s = 0.f;
        for (int j = 0; j < 32; ++j) s += wb[j] * eg1[j];
        for (int j = 0; j < 32; ++j) s += wb[32 + j] * eg2[j];
        blk = s + be[k];
    }
    float v = scoring[b * 16 + k] + blk;
    sval[b][k] = v > 0.f ? v : 0.f;
    __syncthreads();

    if (t < 4) {
        float h1[16], h2[8], h3[4];
        for (int o = 0; o < 16; ++o) {
            float a = m1b[t * 16 + o];
            for (int i = 0; i < 16; ++i) a += m1w[(t * 16 + o) * 16 + i] * sval[t][i];
            h1[o] = a > 0.f ? a : 0.f;
        }
        for (int o = 0; o < 8; ++o) {
            float a = m2b[t * 8 + o];
            for (int i = 0; i < 16; ++i) a += m2w[(t * 8 + o) * 16 + i] * h1[i];
            h2[o] = a > 0.f ? a : 0.f;
        }
        for (int o = 0; o < 4; ++o) {
            float a = m3b[t * 4 + o];
            for (int i = 0; i < 8; ++i) a += m3w[(t * 4 + o) * 8 + i] * h2[i];
            h3[o] = a > 0.f ? a : 0.f;
        }
        float z = sb[t];
        for (int i = 0; i < 4; ++i) z += sw[t * 4 + i] * h3[i];
        scores[t] = 1.0f / (1.0f + expf(-z));
    }
    __syncthreads();

    if (t == 0) {
        const int ord[4] = {0, 1, 3, 2};   // (nc, in, ec, ie)
        float av = avg_v[0];
        float acc = 0.f;
        for (int j = 0; j < 4; ++j) {
            float sc = scores[ord[j]];
            out[2 + j] = sc;
            acc += -logf(sc);
        }
        float ged = acc * av;
        out[1] = ged;
        out[0] = expf(-ged / av);
    }
}

extern "C" void kernel_launch(void* const* d_in, const int* in_sizes, int n_in,
                              void* d_out, int out_size, void* d_ws, size_t ws_size,
                              hipStream_t stream) {
    const float* emb1  = (const float*)d_in[0];
    const float* emb2  = (const float*)d_in[1];
    const float* adj1  = (const float*)d_in[2];
    const float* adj2  = (const float*)d_in[3];
    const float* eat1  = (const float*)d_in[4];
    const float* eat2  = (const float*)d_in[5];
    const float* eadj1 = (const float*)d_in[6];
    const float* eadj2 = (const float*)d_in[7];
    const float* avg_v = (const float*)d_in[8];
    const float* Wn    = (const float*)d_in[9];
    const float* Wbn   = (const float*)d_in[10];
    const float* bn    = (const float*)d_in[11];
    const float* We    = (const float*)d_in[12];
    const float* Wbe   = (const float*)d_in[13];
    const float* be    = (const float*)d_in[14];
    const float* m1w   = (const float*)d_in[15];
    const float* m1b   = (const float*)d_in[16];
    const float* m2w   = (const float*)d_in[17];
    const float* m2b   = (const float*)d_in[18];
    const float* m3w   = (const float*)d_in[19];
    const float* m3b   = (const float*)d_in[20];
    const float* sw    = (const float*)d_in[21];
    const float* sb    = (const float*)d_in[22];

    int Nn = in_sizes[0] / 32;   // 6000 nodes
    int Ne = in_sizes[4] / 16;   // 6000 edges
    int N = Nn;                  // == Ne here

    // Slab sizing: target SLAB_R rows/slab, adapt to ws_size if needed.
    size_t availF = ws_size / 4;
    size_t reserveF = 8 * (size_t)N + 4096;          // small vectors + tail
    size_t perMat = (availF > reserveF) ? (availF - reserveF) / 2 : 0;
    int maxSlabs = (int)(perMat / LDP);
    int nSlabs = (N + SLAB_R - 1) / SLAB_R;          // 188
    if (nSlabs > maxSlabs) nSlabs = maxSlabs > 0 ? maxSlabs : 1;
    int R = (N + nSlabs - 1) / nSlabs;
    nSlabs = (N + R - 1) / R;

    float* ws  = (float*)d_ws;
    float* P   = ws;                       // [2][nSlabs][LDP] partials, reused per phase
    float* c1  = P + (size_t)2 * nSlabs * LDP;
    float* d1  = c1 + N;
    float* c2  = d1 + N;
    float* d2  = c2 + N;
    float* ce1 = d2 + N;
    float* ce2 = ce1 + N;
    float* n1  = ce2 + N;      // [s(32), p(32), q(32)]
    float* n2  = n1 + 96;
    float* eg1 = n2 + 96;      // [s(16), p(16)]
    float* eg2 = eg1 + 32;
    float* scoring = eg2 + 32; // [4][16]
    // zero all accumulated outputs: c1..d2,ce1,ce2 (6N) + n/eg/scoring (320)
    hipMemsetAsync(c1, 0, (6 * (size_t)N + 320) * sizeof(float), stream);

    dim3 blk(THREADS);
    int colChunks = (N + THREADS * 4 - 1) / (THREADS * 4);   // 6
    dim3 gridS(colChunks, nSlabs, 2);                        // 6 x 188 x 2 = 2256 blocks
    dim3 gridR(colChunks, 2, RGROUPS);

    // Phase 1: unweighted colsums of adj1+adj2
    colsum_tile_kernel<false><<<gridS, blk, 0, stream>>>(adj1, adj2, nullptr, nullptr, P, N, nSlabs, R);
    reduce_atomic_kernel<<<gridR, blk, 0, stream>>>(P, c1, c2, N, nSlabs);
    // Phase 2: weighted colsums (re-read adj1+adj2; partially L3-resident)
    colsum_tile_kernel<true ><<<gridS, blk, 0, stream>>>(adj1, adj2, c1, c2, P, N, nSlabs, R);
    reduce_atomic_kernel<<<gridR, blk, 0, stream>>>(P, d1, d2, N, nSlabs);
    // Phase 3: edge adjacency colsums
    colsum_tile_kernel<false><<<gridS, blk, 0, stream>>>(eadj1, eadj2, nullptr, nullptr, P, N, nSlabs, R);
    reduce_atomic_kernel<<<gridR, blk, 0, stream>>>(P, ce1, ce2, N, nSlabs);

    feat_all_kernel<<<dim3(16, 4), blk, 0, stream>>>(emb1, emb2, eat1, eat2,
                                                     c1, d1, c2, d2, ce1, ce2,
                                                     n1, n2, eg1, eg2, Nn, Ne);

    scoring_kernel<<<dim3(16, 4), blk, 0, stream>>>(Wn, We, n1, n2, eg1, eg2, scoring);

    final_kernel<<<1, 64, 0, stream>>>(scoring, n1, n2, eg1, eg2,
                                       Wbn, bn, Wbe, be,
                                       m1w, m1b, m2w, m2b, m3w, m3b, sw, sb,
                                       avg_v, (float*)d_out);
}